// Round 16
// baseline (165.756 us; speedup 1.0000x reference)
//
#include <hip/hip_runtime.h>
#include <hip/hip_bf16.h>
#include <stdint.h>

#define S_LEN 4096
#define D_MODEL 1024
#define N_HEADS 16
#define D_HEAD 64
#define LDQKV 3072
#define SCALE_LOG2E 0.1803368787f   // (1/sqrt(64)) * log2(e)

typedef __attribute__((ext_vector_type(4))) float f32x4;
typedef __attribute__((ext_vector_type(8))) __bf16 bf16x8;
typedef __attribute__((ext_vector_type(4))) __bf16 bf16x4;

__device__ __forceinline__ unsigned short f2bf(float f) {
    union { float f; unsigned u; } x{f};
    unsigned r = x.u + 0x7fff + ((x.u >> 16) & 1);
    return (unsigned short)(r >> 16);
}

__device__ __forceinline__ void gld_lds16(const void* g, void* l) {
    __builtin_amdgcn_global_load_lds(
        (const __attribute__((address_space(1))) unsigned int*)g,
        (__attribute__((address_space(3))) unsigned int*)l, 16, 0, 0);
}

// ---------------- fused prep: x->bf16, weights->bf16, RoPE tables ----------------
__global__ __launch_bounds__(256) void prep_k(const float* __restrict__ x,
                                              const float* __restrict__ Wq,
                                              const float* __restrict__ Wk,
                                              const float* __restrict__ Wv,
                                              const float* __restrict__ Wo,
                                              const int* __restrict__ pos,
                                              unsigned short* __restrict__ xb,
                                              unsigned short* __restrict__ Wb,
                                              float* __restrict__ ct,
                                              float* __restrict__ st) {
    int b = blockIdx.x;
    if (b < 4096) {
        int i = (b * 256 + threadIdx.x) * 4;
        float4 v = *(const float4*)&x[i];
        ushort4 o;
        o.x = f2bf(v.x); o.y = f2bf(v.y); o.z = f2bf(v.z); o.w = f2bf(v.w);
        *(ushort4*)&xb[i] = o;
    } else if (b < 8192) {
        int i = ((b - 4096) * 256 + threadIdx.x) * 4;   // over 4 x 1M
        int sel = i >> 20;
        int off = i & ((1 << 20) - 1);
        const float* src = (sel == 0) ? Wq : (sel == 1) ? Wk : (sel == 2) ? Wv : Wo;
        float4 v = *(const float4*)&src[off];
        ushort4 o;
        o.x = f2bf(v.x); o.y = f2bf(v.y); o.z = f2bf(v.z); o.w = f2bf(v.w);
        *(ushort4*)&Wb[i] = o;
    } else {
        // extended table [4096][64]: k<32 real RoPE, k>=32 identity (for V cols)
        int i = (b - 8192) * 256 + threadIdx.x;   // [0, 4096*64)
        int s = i >> 6, k = i & 63;
        if (k < 32) {
            float invf = __builtin_exp2f(-(float)(2 * k) * (1.0f / 64.0f) * 13.287712379549449f);
            float ang = (float)pos[s] * invf;
            ct[i] = cosf(ang);
            st[i] = sinf(ang);
        } else {
            ct[i] = 1.0f;
            st[i] = 0.0f;
        }
    }
}

// ---------------- V transpose: QKV V-cols [S][3072 (+2048)] -> Vt [1024][S] ----------------
__global__ __launch_bounds__(256) void vtrans_k(const unsigned short* __restrict__ src,
                                                unsigned short* __restrict__ dst) {
    __shared__ unsigned short tile[64 * 68];
    const int bs = blockIdx.x * 64;   // s tile
    const int bd = blockIdx.y * 64;   // d tile
    const int t = threadIdx.x;
    {
        int col = (t & 7) * 8;
        #pragma unroll
        for (int rr = 0; rr < 2; ++rr) {
            int row = rr * 32 + (t >> 3);
            const unsigned short* g = src + (size_t)(bs + row) * LDQKV + bd + col;
            ushort4 a = *(const ushort4*)g;
            ushort4 b = *(const ushort4*)(g + 4);
            *(ushort4*)&tile[row * 68 + col] = a;
            *(ushort4*)&tile[row * 68 + col + 4] = b;
        }
    }
    __syncthreads();
    {
        int dl = t >> 2;             // 0..63 d row
        int sc = (t & 3) * 16;       // s chunk
        ushort4 o[4];
        #pragma unroll
        for (int e = 0; e < 16; ++e)
            ((unsigned short*)o)[e] = tile[(sc + e) * 68 + dl];
        unsigned short* g = dst + (size_t)(bd + dl) * S_LEN + bs + sc;
        *(ushort4*)(g + 0)  = o[0];
        *(ushort4*)(g + 4)  = o[1];
        *(ushort4*)(g + 8)  = o[2];
        *(ushort4*)(g + 12) = o[3];
    }
}

// ---------------- fused QKV GEMM: C[S][3072] = x * [Wq;Wk;Wv]^T ----------------
__global__ __launch_bounds__(256) void gemm_qkv_k(const unsigned short* __restrict__ A,
                                                  const unsigned short* __restrict__ B,
                                                  unsigned short* __restrict__ C,
                                                  const float* __restrict__ ct,
                                                  const float* __restrict__ st) {
    __shared__ unsigned short lA[128 * 64];
    __shared__ unsigned short lB[128 * 64];
    const int t = threadIdx.x, w = t >> 6, l = t & 63;
    const int tm = blockIdx.y * 128, tn = blockIdx.x * 128;
    const int wm = (w >> 1) * 64, wn = (w & 1) * 64;
    const int g = l >> 4, ln = l & 15;

    f32x4 acc[4][4] = {};

    for (int k0 = 0; k0 < 1024; k0 += 64) {
        #pragma unroll
        for (int r = 0; r < 4; ++r) {
            int row = 8 * (4 * r + w) + (l >> 3);
            gld_lds16(A + (size_t)(tm + row) * 1024 + k0 + (l & 7) * 8, &lA[(4 * r + w) * 512]);
            gld_lds16(B + (size_t)(tn + row) * 1024 + k0 + (l & 7) * 8, &lB[(4 * r + w) * 512]);
        }
        asm volatile("s_waitcnt vmcnt(0)" ::: "memory");
        __syncthreads();

        #pragma unroll
        for (int kk = 0; kk < 2; ++kk) {
            bf16x8 af[4], bf[4];
            #pragma unroll
            for (int i = 0; i < 4; ++i) {
                af[i] = *(const bf16x8*)&lA[(wm + i * 16 + ln) * 64 + kk * 32 + g * 8];
                bf[i] = *(const bf16x8*)&lB[(wn + i * 16 + ln) * 64 + kk * 32 + g * 8];
            }
            #pragma unroll
            for (int i = 0; i < 4; ++i)
                #pragma unroll
                for (int j = 0; j < 4; ++j)
                    acc[i][j] = __builtin_amdgcn_mfma_f32_16x16x32_bf16(af[i], bf[j], acc[i][j], 0, 0, 0);
        }
        __syncthreads();
    }

    // epilogue: RoPE (identity for V) + Q pre-scale, all lanes same path
    #pragma unroll
    for (int i = 0; i < 4; ++i) {
        #pragma unroll
        for (int j = 0; j < 4; ++j) {
            int col = tn + wn + j * 16 + ln;
            int dd = col & 63;
            int tb = ((col >= 2048) ? 32 : 0) + (dd >> 1);
            float scl = (col < 1024) ? SCALE_LOG2E : 1.0f;
            #pragma unroll
            for (int r = 0; r < 4; ++r) {
                int row = tm + wm + i * 16 + g * 4 + r;
                float v = acc[i][j][r];
                float p = __shfl_xor(v, 1, 64);
                float c = ct[row * 64 + tb];
                float s = st[row * 64 + tb];
                v = ((dd & 1) ? (s * p + c * v) : (c * v - s * p)) * scl;
                C[(size_t)row * LDQKV + col] = f2bf(v);
            }
        }
    }
}

// ---------------- out GEMM: out[S][1024] f32 = ctx * Wo^T, 64x128 tiles ----------------
__global__ __launch_bounds__(256) void gemm_o_k(const unsigned short* __restrict__ A,
                                                const unsigned short* __restrict__ B,
                                                float* __restrict__ C) {
    __shared__ unsigned short lA[64 * 64];    // 8 KB
    __shared__ unsigned short lB[128 * 64];   // 16 KB
    const int t = threadIdx.x, w = t >> 6, l = t & 63;
    const int tm = blockIdx.y * 64, tn = blockIdx.x * 128;
    const int wm = (w >> 1) * 32, wn = (w & 1) * 64;
    const int g = l >> 4, ln = l & 15;

    f32x4 acc[2][4] = {};

    for (int k0 = 0; k0 < 1024; k0 += 64) {
        #pragma unroll
        for (int r = 0; r < 2; ++r) {
            int row = r * 32 + w * 8 + (l >> 3);
            gld_lds16(A + (size_t)(tm + row) * 1024 + k0 + (l & 7) * 8, &lA[(r * 32 + w * 8) * 64]);
        }
        #pragma unroll
        for (int r = 0; r < 4; ++r) {
            int row = 8 * (4 * r + w) + (l >> 3);
            gld_lds16(B + (size_t)(tn + row) * 1024 + k0 + (l & 7) * 8, &lB[(4 * r + w) * 512]);
        }
        asm volatile("s_waitcnt vmcnt(0)" ::: "memory");
        __syncthreads();

        #pragma unroll
        for (int kk = 0; kk < 2; ++kk) {
            bf16x8 af[2], bf[4];
            #pragma unroll
            for (int i = 0; i < 2; ++i)
                af[i] = *(const bf16x8*)&lA[(wm + i * 16 + ln) * 64 + kk * 32 + g * 8];
            #pragma unroll
            for (int j = 0; j < 4; ++j)
                bf[j] = *(const bf16x8*)&lB[(wn + j * 16 + ln) * 64 + kk * 32 + g * 8];
            #pragma unroll
            for (int i = 0; i < 2; ++i)
                #pragma unroll
                for (int j = 0; j < 4; ++j)
                    acc[i][j] = __builtin_amdgcn_mfma_f32_16x16x32_bf16(af[i], bf[j], acc[i][j], 0, 0, 0);
        }
        __syncthreads();
    }

    #pragma unroll
    for (int i = 0; i < 2; ++i)
        #pragma unroll
        for (int j = 0; j < 4; ++j) {
            int col = tn + wn + j * 16 + ln;
            #pragma unroll
            for (int r = 0; r < 4; ++r) {
                int row = tm + wm + i * 16 + g * 4 + r;
                C[(size_t)row * 1024 + col] = acc[i][j][r];
            }
        }
}

// ---------------- causal flash attention, PAIRED q-tiles + counted-vmcnt pipeline ----
// grid: (16 heads, 32 pairs). block: 512 thr = 8 waves; waves 0-3 -> qA,
// waves 4-7 -> qB=63-qA (uniform 65 tile-passes per block).
// NEW (T4): 3 LDS buffers, prefetch distance 2, raw s_barrier with
// s_waitcnt vmcnt(2) (each wave issues 2 gld_lds per stage; leaving the
// newest tile's loads in flight across the barrier). The old
// __syncthreads() drained vmcnt(0) every tile -> per-tile latency wall.
// Safety: per-wave vmcnt BEFORE the barrier => all waves' tile-kt loads
// landed before any wave computes kt; barrier at loop head protects the
// buffer overwritten 3 iterations later; final iteration waits vmcnt(0).
__device__ __forceinline__ void stage8(const unsigned short* __restrict__ Kb,
                                       const unsigned short* __restrict__ Vt,
                                       unsigned short* lK, unsigned short* lV,
                                       int h, int kt, int w, int l) {
    const int half = w & 3;
    const int chunk = (l & 7) ^ (l >> 3);   // source pre-swizzle (row&7 == l>>3)
    if (w < 4) {
        #pragma unroll
        for (int r2 = 0; r2 < 2; ++r2) {
            int row = half * 16 + r2 * 8 + (l >> 3);
            gld_lds16(Kb + (size_t)(kt * 64 + row) * LDQKV + h * 64 + chunk * 8,
                      lK + half * 1024 + r2 * 512);
        }
    } else {
        #pragma unroll
        for (int r2 = 0; r2 < 2; ++r2) {
            int row = half * 16 + r2 * 8 + (l >> 3);
            gld_lds16(Vt + (size_t)(h * 64 + row) * S_LEN + kt * 64 + chunk * 8,
                      lV + half * 1024 + r2 * 512);
        }
    }
}

__global__ __launch_bounds__(512) void attn_k(const unsigned short* __restrict__ Qb,
                                              const unsigned short* __restrict__ Kb,
                                              const unsigned short* __restrict__ Vt,
                                              unsigned short* __restrict__ ctxb) {
    __shared__ unsigned short lK[3][64 * 64];   // 24 KB
    __shared__ unsigned short lV[3][64 * 64];   // 24 KB
    __shared__ unsigned short lP[8][16 * 64];   // 16 KB (wave-private P)

    const int t = threadIdx.x, w = t >> 6, l = t & 63;
    const int wv = w & 3;
    const int sel = w >> 2;
    const int h = blockIdx.x;
    const int qA = blockIdx.y;              // 0..31
    const int qB = 63 - qA;                 // 32..63
    const int qT = sel ? qB : qA;
    const int q0 = qT * 64 + wv * 16;
    const int g = l >> 4, ln = l & 15;

    bf16x8 aq[2];
    #pragma unroll
    for (int kk = 0; kk < 2; ++kk)
        aq[kk] = *(const bf16x8*)&Qb[(size_t)(q0 + ln) * LDQKV + h * 64 + kk * 32 + g * 8];

    f32x4 acc[4] = {};
    float rm = -INFINITY, rs = 0.0f;
    char* lpw = (char*)&lP[w][0];

    // prologue: stage tiles 0 and 1 (qB >= 32 always, so tile 1 exists)
    stage8(Kb, Vt, &lK[0][0], &lV[0][0], h, 0, w, l);
    stage8(Kb, Vt, &lK[1][0], &lV[1][0], h, 1, w, l);

    for (int kt = 0; kt <= qB; ++kt) {
        // counted wait: tiles > kt stay in flight (2 loads/wave/tile)
        if (kt < qB) asm volatile("s_waitcnt vmcnt(2)" ::: "memory");
        else         asm volatile("s_waitcnt vmcnt(0)" ::: "memory");
        __builtin_amdgcn_sched_barrier(0);
        __builtin_amdgcn_s_barrier();
        __builtin_amdgcn_sched_barrier(0);

        // prefetch tile kt+2 into the buffer read at tile kt-1 (all waves
        // finished it before the barrier above)
        if (kt + 2 <= qB) {
            int nb = (kt + 2) % 3;
            stage8(Kb, Vt, &lK[nb][0], &lV[nb][0], h, kt + 2, w, l);
        }

        if (kt <= qT) {
            const int cb = kt % 3;
            float p[16];
            __builtin_amdgcn_s_setprio(1);
            #pragma unroll
            for (int ct = 0; ct < 4; ++ct) {
                f32x4 z = {};
                #pragma unroll
                for (int kk = 0; kk < 2; ++kk) {
                    int row = ct * 16 + ln;
                    int off = (row * 128 + kk * 64 + g * 16) ^ ((row & 7) << 4);
                    bf16x8 ak = *(const bf16x8*)((const char*)&lK[cb][0] + off);
                    z = __builtin_amdgcn_mfma_f32_16x16x32_bf16(ak, aq[kk], z, 0, 0, 0);
                }
                #pragma unroll
                for (int r = 0; r < 4; ++r) p[ct * 4 + r] = z[r];
            }
            __builtin_amdgcn_s_setprio(0);

            if (kt == qT) {
                int qg = q0 + ln;
                #pragma unroll
                for (int ct = 0; ct < 4; ++ct)
                    #pragma unroll
                    for (int r = 0; r < 4; ++r)
                        if (kt * 64 + ct * 16 + g * 4 + r > qg) p[ct * 4 + r] = -INFINITY;
            }

            float pmax = fmaxf(p[0], p[1]);
            #pragma unroll
            for (int i = 2; i < 16; i += 2)
                pmax = fmaxf(fmaxf(pmax, p[i]), p[i + 1]);
            pmax = fmaxf(pmax, __shfl_xor(pmax, 16, 64));
            pmax = fmaxf(pmax, __shfl_xor(pmax, 32, 64));
            if (__any(pmax > rm + 8.0f)) {
                float mn = fmaxf(rm, pmax);
                float fac = __builtin_amdgcn_exp2f(rm - mn);
                rm = mn;
                rs *= fac;
                #pragma unroll
                for (int mb = 0; mb < 4; ++mb) {
                    f32x4 a = acc[mb];
                    #pragma unroll
                    for (int r = 0; r < 4; ++r) a[r] *= fac;
                    acc[mb] = a;
                }
            }
            float ps = 0.0f;
            #pragma unroll
            for (int i = 0; i < 16; ++i) {
                float e = __builtin_amdgcn_exp2f(p[i] - rm);
                p[i] = e;
                ps += e;
            }
            ps += __shfl_xor(ps, 16, 64);
            ps += __shfl_xor(ps, 32, 64);
            rs += ps;

            // pack P (bf16) to wave-private LDS (compiler-ordered RAW)
            #pragma unroll
            for (int ct = 0; ct < 4; ++ct) {
                bf16x4 pv;
                pv[0] = (__bf16)p[ct * 4 + 0];
                pv[1] = (__bf16)p[ct * 4 + 1];
                pv[2] = (__bf16)p[ct * 4 + 2];
                pv[3] = (__bf16)p[ct * 4 + 3];
                int off = (ln * 128 + ct * 32 + g * 8) ^ ((ln & 7) << 4);
                *(bf16x4*)(lpw + off) = pv;
            }

            __builtin_amdgcn_s_setprio(1);
            #pragma unroll
            for (int mb = 0; mb < 4; ++mb) {
                #pragma unroll
                for (int kc = 0; kc < 2; ++kc) {
                    int vrow = mb * 16 + ln;
                    int voff = (vrow * 128 + kc * 64 + g * 16) ^ ((vrow & 7) << 4);
                    bf16x8 av = *(const bf16x8*)((const char*)&lV[cb][0] + voff);
                    int poff = (ln * 128 + kc * 64 + g * 16) ^ ((ln & 7) << 4);
                    bf16x8 bp = *(const bf16x8*)(lpw + poff);
                    acc[mb] = __builtin_amdgcn_mfma_f32_16x16x32_bf16(av, bp, acc[mb], 0, 0, 0);
                }
            }
            __builtin_amdgcn_s_setprio(0);
        }
    }

    float inv = 1.0f / rs;
    #pragma unroll
    for (int mb = 0; mb < 4; ++mb) {
        bf16x4 o;
        #pragma unroll
        for (int r = 0; r < 4; ++r) o[r] = (__bf16)(acc[mb][r] * inv);
        *(bf16x4*)&ctxb[(size_t)(q0 + ln) * D_MODEL + h * 64 + mb * 16 + g * 4] = o;
    }
}

// ---------------- host side ----------------
extern "C" void kernel_launch(void* const* d_in, const int* in_sizes, int n_in,
                              void* d_out, int out_size, void* d_ws, size_t ws_size,
                              hipStream_t stream) {
    const float* x  = (const float*)d_in[0];
    const float* Wq = (const float*)d_in[1];
    const float* Wk = (const float*)d_in[2];
    const float* Wv = (const float*)d_in[3];
    const float* Wo = (const float*)d_in[4];
    const int* tpos = (const int*)d_in[5];
    float* out = (float*)d_out;

    char* ws = (char*)d_ws;
    unsigned short* xb   = (unsigned short*)(ws + 0);            // 8 MB (dead after QKV gemm)
    unsigned short* Wb   = (unsigned short*)(ws + (8u << 20));   // 8 MB (Wq,Wk,Wv,Wo bf16)
    unsigned short* QKV  = (unsigned short*)(ws + (16u << 20));  // 24 MB [S][3072]
    unsigned short* ctxb = (unsigned short*)(ws + (40u << 20));  // 8 MB
    float* costab = (float*)(ws + (48u << 20));                  // 1 MB [4096][64]
    float* sintab = (float*)(ws + (49u << 20));                  // 1 MB
    unsigned short* Vtb  = xb;   // reuse: written by vtrans after QKV gemm

    // prep: x->bf16 | weights->bf16 | extended RoPE tables
    prep_k<<<9216, 256, 0, stream>>>(x, Wq, Wk, Wv, Wo, tpos, xb, Wb, costab, sintab);

    // fused QKV projection with RoPE/scale epilogue: 768 blocks = 3/CU
    gemm_qkv_k<<<dim3(24, 32), 256, 0, stream>>>(xb, Wb, QKV, costab, sintab);

    // V transpose: QKV cols 2048.. -> Vt [1024][S]
    vtrans_k<<<dim3(S_LEN / 64, D_MODEL / 64), 256, 0, stream>>>(QKV + 2048, Vtb);

    // paired causal attention, counted-vmcnt 3-buffer pipeline
    attn_k<<<dim3(N_HEADS, 32), 512, 0, stream>>>(QKV, QKV + 1024, Vtb, ctxb);

    // out projection, 64x128 tiles: 512 blocks = 2/CU
    gemm_o_k<<<dim3(8, 64), 256, 0, stream>>>(ctxb, Wb + 3u * 1024 * 1024, out);
}

// Round 17
// 165.166 us; speedup vs baseline: 1.0036x; 1.0036x over previous
//
#include <hip/hip_runtime.h>
#include <hip/hip_bf16.h>
#include <stdint.h>

#define S_LEN 4096
#define D_MODEL 1024
#define N_HEADS 16
#define D_HEAD 64
#define LDQKV 3072
#define SCALE_LOG2E 0.1803368787f   // (1/sqrt(64)) * log2(e)

typedef __attribute__((ext_vector_type(4))) float f32x4;
typedef __attribute__((ext_vector_type(8))) __bf16 bf16x8;
typedef __attribute__((ext_vector_type(4))) __bf16 bf16x4;

__device__ __forceinline__ unsigned short f2bf(float f) {
    union { float f; unsigned u; } x{f};
    unsigned r = x.u + 0x7fff + ((x.u >> 16) & 1);
    return (unsigned short)(r >> 16);
}

__device__ __forceinline__ void gld_lds16(const void* g, void* l) {
    __builtin_amdgcn_global_load_lds(
        (const __attribute__((address_space(1))) unsigned int*)g,
        (__attribute__((address_space(3))) unsigned int*)l, 16, 0, 0);
}

// ---------------- fused prep: x->bf16, weights->bf16, RoPE tables ----------------
__global__ __launch_bounds__(256) void prep_k(const float* __restrict__ x,
                                              const float* __restrict__ Wq,
                                              const float* __restrict__ Wk,
                                              const float* __restrict__ Wv,
                                              const float* __restrict__ Wo,
                                              const int* __restrict__ pos,
                                              unsigned short* __restrict__ xb,
                                              unsigned short* __restrict__ Wb,
                                              float* __restrict__ ct,
                                              float* __restrict__ st) {
    int b = blockIdx.x;
    if (b < 4096) {
        int i = (b * 256 + threadIdx.x) * 4;
        float4 v = *(const float4*)&x[i];
        ushort4 o;
        o.x = f2bf(v.x); o.y = f2bf(v.y); o.z = f2bf(v.z); o.w = f2bf(v.w);
        *(ushort4*)&xb[i] = o;
    } else if (b < 8192) {
        int i = ((b - 4096) * 256 + threadIdx.x) * 4;   // over 4 x 1M
        int sel = i >> 20;
        int off = i & ((1 << 20) - 1);
        const float* src = (sel == 0) ? Wq : (sel == 1) ? Wk : (sel == 2) ? Wv : Wo;
        float4 v = *(const float4*)&src[off];
        ushort4 o;
        o.x = f2bf(v.x); o.y = f2bf(v.y); o.z = f2bf(v.z); o.w = f2bf(v.w);
        *(ushort4*)&Wb[i] = o;
    } else {
        // extended table [4096][64]: k<32 real RoPE, k>=32 identity (for V cols)
        int i = (b - 8192) * 256 + threadIdx.x;   // [0, 4096*64)
        int s = i >> 6, k = i & 63;
        if (k < 32) {
            float invf = __builtin_exp2f(-(float)(2 * k) * (1.0f / 64.0f) * 13.287712379549449f);
            float ang = (float)pos[s] * invf;
            ct[i] = cosf(ang);
            st[i] = sinf(ang);
        } else {
            ct[i] = 1.0f;
            st[i] = 0.0f;
        }
    }
}

// ---------------- V transpose: QKV V-cols [S][3072 (+2048)] -> Vt [1024][S] ----------------
__global__ __launch_bounds__(256) void vtrans_k(const unsigned short* __restrict__ src,
                                                unsigned short* __restrict__ dst) {
    __shared__ unsigned short tile[64 * 68];
    const int bs = blockIdx.x * 64;   // s tile
    const int bd = blockIdx.y * 64;   // d tile
    const int t = threadIdx.x;
    {
        int col = (t & 7) * 8;
        #pragma unroll
        for (int rr = 0; rr < 2; ++rr) {
            int row = rr * 32 + (t >> 3);
            const unsigned short* g = src + (size_t)(bs + row) * LDQKV + bd + col;
            ushort4 a = *(const ushort4*)g;
            ushort4 b = *(const ushort4*)(g + 4);
            *(ushort4*)&tile[row * 68 + col] = a;
            *(ushort4*)&tile[row * 68 + col + 4] = b;
        }
    }
    __syncthreads();
    {
        int dl = t >> 2;             // 0..63 d row
        int sc = (t & 3) * 16;       // s chunk
        ushort4 o[4];
        #pragma unroll
        for (int e = 0; e < 16; ++e)
            ((unsigned short*)o)[e] = tile[(sc + e) * 68 + dl];
        unsigned short* g = dst + (size_t)(bd + dl) * S_LEN + bs + sc;
        *(ushort4*)(g + 0)  = o[0];
        *(ushort4*)(g + 4)  = o[1];
        *(ushort4*)(g + 8)  = o[2];
        *(ushort4*)(g + 12) = o[3];
    }
}

// ---------------- fused QKV GEMM: C[S][3072] = x * [Wq;Wk;Wv]^T ----------------
__global__ __launch_bounds__(256) void gemm_qkv_k(const unsigned short* __restrict__ A,
                                                  const unsigned short* __restrict__ B,
                                                  unsigned short* __restrict__ C,
                                                  const float* __restrict__ ct,
                                                  const float* __restrict__ st) {
    __shared__ unsigned short lA[128 * 64];
    __shared__ unsigned short lB[128 * 64];
    const int t = threadIdx.x, w = t >> 6, l = t & 63;
    const int tm = blockIdx.y * 128, tn = blockIdx.x * 128;
    const int wm = (w >> 1) * 64, wn = (w & 1) * 64;
    const int g = l >> 4, ln = l & 15;

    f32x4 acc[4][4] = {};

    for (int k0 = 0; k0 < 1024; k0 += 64) {
        #pragma unroll
        for (int r = 0; r < 4; ++r) {
            int row = 8 * (4 * r + w) + (l >> 3);
            gld_lds16(A + (size_t)(tm + row) * 1024 + k0 + (l & 7) * 8, &lA[(4 * r + w) * 512]);
            gld_lds16(B + (size_t)(tn + row) * 1024 + k0 + (l & 7) * 8, &lB[(4 * r + w) * 512]);
        }
        asm volatile("s_waitcnt vmcnt(0)" ::: "memory");
        __syncthreads();

        #pragma unroll
        for (int kk = 0; kk < 2; ++kk) {
            bf16x8 af[4], bf[4];
            #pragma unroll
            for (int i = 0; i < 4; ++i) {
                af[i] = *(const bf16x8*)&lA[(wm + i * 16 + ln) * 64 + kk * 32 + g * 8];
                bf[i] = *(const bf16x8*)&lB[(wn + i * 16 + ln) * 64 + kk * 32 + g * 8];
            }
            #pragma unroll
            for (int i = 0; i < 4; ++i)
                #pragma unroll
                for (int j = 0; j < 4; ++j)
                    acc[i][j] = __builtin_amdgcn_mfma_f32_16x16x32_bf16(af[i], bf[j], acc[i][j], 0, 0, 0);
        }
        __syncthreads();
    }

    // epilogue: RoPE (identity for V) + Q pre-scale, all lanes same path
    #pragma unroll
    for (int i = 0; i < 4; ++i) {
        #pragma unroll
        for (int j = 0; j < 4; ++j) {
            int col = tn + wn + j * 16 + ln;
            int dd = col & 63;
            int tb = ((col >= 2048) ? 32 : 0) + (dd >> 1);
            float scl = (col < 1024) ? SCALE_LOG2E : 1.0f;
            #pragma unroll
            for (int r = 0; r < 4; ++r) {
                int row = tm + wm + i * 16 + g * 4 + r;
                float v = acc[i][j][r];
                float p = __shfl_xor(v, 1, 64);
                float c = ct[row * 64 + tb];
                float s = st[row * 64 + tb];
                v = ((dd & 1) ? (s * p + c * v) : (c * v - s * p)) * scl;
                C[(size_t)row * LDQKV + col] = f2bf(v);
            }
        }
    }
}

// ---------------- out GEMM: out[S][1024] f32 = ctx * Wo^T, 64x128 tiles ----------------
__global__ __launch_bounds__(256) void gemm_o_k(const unsigned short* __restrict__ A,
                                                const unsigned short* __restrict__ B,
                                                float* __restrict__ C) {
    __shared__ unsigned short lA[64 * 64];    // 8 KB
    __shared__ unsigned short lB[128 * 64];   // 16 KB
    const int t = threadIdx.x, w = t >> 6, l = t & 63;
    const int tm = blockIdx.y * 64, tn = blockIdx.x * 128;
    const int wm = (w >> 1) * 32, wn = (w & 1) * 64;
    const int g = l >> 4, ln = l & 15;

    f32x4 acc[2][4] = {};

    for (int k0 = 0; k0 < 1024; k0 += 64) {
        #pragma unroll
        for (int r = 0; r < 2; ++r) {
            int row = r * 32 + w * 8 + (l >> 3);
            gld_lds16(A + (size_t)(tm + row) * 1024 + k0 + (l & 7) * 8, &lA[(r * 32 + w * 8) * 64]);
        }
        #pragma unroll
        for (int r = 0; r < 4; ++r) {
            int row = 8 * (4 * r + w) + (l >> 3);
            gld_lds16(B + (size_t)(tn + row) * 1024 + k0 + (l & 7) * 8, &lB[(4 * r + w) * 512]);
        }
        asm volatile("s_waitcnt vmcnt(0)" ::: "memory");
        __syncthreads();

        #pragma unroll
        for (int kk = 0; kk < 2; ++kk) {
            bf16x8 af[2], bf[4];
            #pragma unroll
            for (int i = 0; i < 2; ++i)
                af[i] = *(const bf16x8*)&lA[(wm + i * 16 + ln) * 64 + kk * 32 + g * 8];
            #pragma unroll
            for (int j = 0; j < 4; ++j)
                bf[j] = *(const bf16x8*)&lB[(wn + j * 16 + ln) * 64 + kk * 32 + g * 8];
            #pragma unroll
            for (int i = 0; i < 2; ++i)
                #pragma unroll
                for (int j = 0; j < 4; ++j)
                    acc[i][j] = __builtin_amdgcn_mfma_f32_16x16x32_bf16(af[i], bf[j], acc[i][j], 0, 0, 0);
        }
        __syncthreads();
    }

    #pragma unroll
    for (int i = 0; i < 2; ++i)
        #pragma unroll
        for (int j = 0; j < 4; ++j) {
            int col = tn + wn + j * 16 + ln;
            #pragma unroll
            for (int r = 0; r < 4; ++r) {
                int row = tm + wm + i * 16 + g * 4 + r;
                C[(size_t)row * 1024 + col] = acc[i][j][r];
            }
        }
}

// ---------------- causal flash attention, PAIRED q-tiles for load balance ----
// grid: (16 heads, 32 pairs). block: 512 thr = 8 waves. Waves 0-3 own q-tile
// qA=blockIdx.y, waves 4-7 own qB=63-qA -> every block computes exactly 65
// kv-tile passes (uniform). Both tiles share the staged K/V for kt<=qA.
// ONE barrier per kv-tile; P buffer is wave-private (compiler-ordered).
__device__ __forceinline__ void stage8(const unsigned short* __restrict__ Kb,
                                       const unsigned short* __restrict__ Vt,
                                       unsigned short* lK, unsigned short* lV,
                                       int h, int kt, int w, int l) {
    const int half = w & 3;
    const int chunk = (l & 7) ^ (l >> 3);   // source pre-swizzle (row&7 == l>>3)
    if (w < 4) {
        #pragma unroll
        for (int r2 = 0; r2 < 2; ++r2) {
            int row = half * 16 + r2 * 8 + (l >> 3);
            gld_lds16(Kb + (size_t)(kt * 64 + row) * LDQKV + h * 64 + chunk * 8,
                      lK + half * 1024 + r2 * 512);
        }
    } else {
        #pragma unroll
        for (int r2 = 0; r2 < 2; ++r2) {
            int row = half * 16 + r2 * 8 + (l >> 3);
            gld_lds16(Vt + (size_t)(h * 64 + row) * S_LEN + kt * 64 + chunk * 8,
                      lV + half * 1024 + r2 * 512);
        }
    }
}

__global__ __launch_bounds__(512) void attn_k(const unsigned short* __restrict__ Qb,
                                              const unsigned short* __restrict__ Kb,
                                              const unsigned short* __restrict__ Vt,
                                              unsigned short* __restrict__ ctxb) {
    __shared__ unsigned short lK[2][64 * 64];
    __shared__ unsigned short lV[2][64 * 64];
    __shared__ unsigned short lP[8][16 * 64];

    const int t = threadIdx.x, w = t >> 6, l = t & 63;
    const int wv = w & 3;
    const int sel = w >> 2;
    const int h = blockIdx.x;
    const int qA = blockIdx.y;              // 0..31
    const int qB = 63 - qA;                 // 32..63
    const int qT = sel ? qB : qA;
    const int q0 = qT * 64 + wv * 16;
    const int g = l >> 4, ln = l & 15;

    bf16x8 aq[2];
    #pragma unroll
    for (int kk = 0; kk < 2; ++kk)
        aq[kk] = *(const bf16x8*)&Qb[(size_t)(q0 + ln) * LDQKV + h * 64 + kk * 32 + g * 8];

    f32x4 acc[4] = {};
    float rm = -INFINITY, rs = 0.0f;
    char* lpw = (char*)&lP[w][0];

    stage8(Kb, Vt, &lK[0][0], &lV[0][0], h, 0, w, l);
    asm volatile("s_waitcnt vmcnt(0)" ::: "memory");
    __syncthreads();

    int cur = 0;
    for (int kt = 0; kt <= qB; ++kt) {
        if (kt < qB)
            stage8(Kb, Vt, &lK[cur ^ 1][0], &lV[cur ^ 1][0], h, kt + 1, w, l);

        if (kt <= qT) {
            float p[16];
            __builtin_amdgcn_s_setprio(1);
            #pragma unroll
            for (int ct = 0; ct < 4; ++ct) {
                f32x4 z = {};
                #pragma unroll
                for (int kk = 0; kk < 2; ++kk) {
                    int row = ct * 16 + ln;
                    int off = (row * 128 + kk * 64 + g * 16) ^ ((row & 7) << 4);
                    bf16x8 ak = *(const bf16x8*)((const char*)&lK[cur][0] + off);
                    z = __builtin_amdgcn_mfma_f32_16x16x32_bf16(ak, aq[kk], z, 0, 0, 0);
                }
                #pragma unroll
                for (int r = 0; r < 4; ++r) p[ct * 4 + r] = z[r];
            }
            __builtin_amdgcn_s_setprio(0);

            if (kt == qT) {
                int qg = q0 + ln;
                #pragma unroll
                for (int ct = 0; ct < 4; ++ct)
                    #pragma unroll
                    for (int r = 0; r < 4; ++r)
                        if (kt * 64 + ct * 16 + g * 4 + r > qg) p[ct * 4 + r] = -INFINITY;
            }

            float pmax = fmaxf(p[0], p[1]);
            #pragma unroll
            for (int i = 2; i < 16; i += 2)
                pmax = fmaxf(fmaxf(pmax, p[i]), p[i + 1]);
            pmax = fmaxf(pmax, __shfl_xor(pmax, 16, 64));
            pmax = fmaxf(pmax, __shfl_xor(pmax, 32, 64));
            if (__any(pmax > rm + 8.0f)) {
                float mn = fmaxf(rm, pmax);
                float fac = __builtin_amdgcn_exp2f(rm - mn);
                rm = mn;
                rs *= fac;
                #pragma unroll
                for (int mb = 0; mb < 4; ++mb) {
                    f32x4 a = acc[mb];
                    #pragma unroll
                    for (int r = 0; r < 4; ++r) a[r] *= fac;
                    acc[mb] = a;
                }
            }
            float ps = 0.0f;
            #pragma unroll
            for (int i = 0; i < 16; ++i) {
                float e = __builtin_amdgcn_exp2f(p[i] - rm);
                p[i] = e;
                ps += e;
            }
            ps += __shfl_xor(ps, 16, 64);
            ps += __shfl_xor(ps, 32, 64);
            rs += ps;

            #pragma unroll
            for (int ct = 0; ct < 4; ++ct) {
                bf16x4 pv;
                pv[0] = (__bf16)p[ct * 4 + 0];
                pv[1] = (__bf16)p[ct * 4 + 1];
                pv[2] = (__bf16)p[ct * 4 + 2];
                pv[3] = (__bf16)p[ct * 4 + 3];
                int off = (ln * 128 + ct * 32 + g * 8) ^ ((ln & 7) << 4);
                *(bf16x4*)(lpw + off) = pv;
            }

            __builtin_amdgcn_s_setprio(1);
            #pragma unroll
            for (int mb = 0; mb < 4; ++mb) {
                #pragma unroll
                for (int kc = 0; kc < 2; ++kc) {
                    int vrow = mb * 16 + ln;
                    int voff = (vrow * 128 + kc * 64 + g * 16) ^ ((vrow & 7) << 4);
                    bf16x8 av = *(const bf16x8*)((const char*)&lV[cur][0] + voff);
                    int poff = (ln * 128 + kc * 64 + g * 16) ^ ((ln & 7) << 4);
                    bf16x8 bp = *(const bf16x8*)(lpw + poff);
                    acc[mb] = __builtin_amdgcn_mfma_f32_16x16x32_bf16(av, bp, acc[mb], 0, 0, 0);
                }
            }
            __builtin_amdgcn_s_setprio(0);
        }

        asm volatile("s_waitcnt vmcnt(0)" ::: "memory");
        __syncthreads();
        cur ^= 1;
    }

    float inv = 1.0f / rs;
    #pragma unroll
    for (int mb = 0; mb < 4; ++mb) {
        bf16x4 o;
        #pragma unroll
        for (int r = 0; r < 4; ++r) o[r] = (__bf16)(acc[mb][r] * inv);
        *(bf16x4*)&ctxb[(size_t)(q0 + ln) * D_MODEL + h * 64 + mb * 16 + g * 4] = o;
    }
}

// ---------------- host side ----------------
extern "C" void kernel_launch(void* const* d_in, const int* in_sizes, int n_in,
                              void* d_out, int out_size, void* d_ws, size_t ws_size,
                              hipStream_t stream) {
    const float* x  = (const float*)d_in[0];
    const float* Wq = (const float*)d_in[1];
    const float* Wk = (const float*)d_in[2];
    const float* Wv = (const float*)d_in[3];
    const float* Wo = (const float*)d_in[4];
    const int* tpos = (const int*)d_in[5];
    float* out = (float*)d_out;

    char* ws = (char*)d_ws;
    unsigned short* xb   = (unsigned short*)(ws + 0);            // 8 MB (dead after QKV gemm)
    unsigned short* Wb   = (unsigned short*)(ws + (8u << 20));   // 8 MB (Wq,Wk,Wv,Wo bf16)
    unsigned short* QKV  = (unsigned short*)(ws + (16u << 20));  // 24 MB [S][3072]
    unsigned short* ctxb = (unsigned short*)(ws + (40u << 20));  // 8 MB
    float* costab = (float*)(ws + (48u << 20));                  // 1 MB [4096][64]
    float* sintab = (float*)(ws + (49u << 20));                  // 1 MB
    unsigned short* Vtb  = xb;   // reuse: written by vtrans after QKV gemm

    // prep: x->bf16 | weights->bf16 | extended RoPE tables
    prep_k<<<9216, 256, 0, stream>>>(x, Wq, Wk, Wv, Wo, tpos, xb, Wb, costab, sintab);

    // fused QKV projection with RoPE/scale epilogue: 768 blocks = 3/CU
    gemm_qkv_k<<<dim3(24, 32), 256, 0, stream>>>(xb, Wb, QKV, costab, sintab);

    // V transpose: QKV cols 2048.. -> Vt [1024][S]
    vtrans_k<<<dim3(S_LEN / 64, D_MODEL / 64), 256, 0, stream>>>(QKV + 2048, Vtb);

    // paired causal attention: 32 balanced blocks per head
    attn_k<<<dim3(N_HEADS, 32), 512, 0, stream>>>(QKV, QKV + 1024, Vtb, ctxb);

    // out projection, 64x128 tiles: 512 blocks = 2/CU
    gemm_o_k<<<dim3(8, 64), 256, 0, stream>>>(ctxb, Wb + 3u * 1024 * 1024, out);
}